// Round 7
// baseline (246.110 us; speedup 1.0000x reference)
//
#include <hip/hip_runtime.h>
#include <hip/hip_bf16.h>

#define N_EMBD 1024
#define N_HEADS 16
#define HD 64
#define TSEQ 2048
#define BATCH 4
#define M_TOT (BATCH*TSEQ)   // 8192

typedef short s16x8 __attribute__((ext_vector_type(8)));
typedef float f32x4 __attribute__((ext_vector_type(4)));

__device__ __forceinline__ void glds16(const void* g, void* l) {
  __builtin_amdgcn_global_load_lds((const __attribute__((address_space(1))) void*)g,
                                   (__attribute__((address_space(3))) void*)l, 16, 0, 0);
}

// exp(s*0.125) = 2^(s * 0.125*log2(e)) via a single hardware v_exp_f32 (R2).
__device__ __forceinline__ float exp_scaled(float s) {
  float r;
  asm("v_exp_f32 %0, %1\n\ts_nop 0" : "=v"(r) : "v"(s * 0.18033688011112042f));
  return r;
}

// pack two f32 -> bf16x2 (src0 in low 16). No builtin on gfx950 (T12/m240).
__device__ __forceinline__ unsigned cvtpk(float lo, float hi) {
  unsigned r;
  asm("v_cvt_pk_bf16_f32 %0, %1, %2" : "=v"(r) : "v"(lo), "v"(hi));
  return r;
}

// ---- cast x fp32 -> bf16, 4 elems/thread ----
__global__ __launch_bounds__(256) void xcast_kernel(const float* __restrict__ x,
                                                    __hip_bfloat16* __restrict__ xb) {
  int i = blockIdx.x * 256 + threadIdx.x;
  float4 f = ((const float4*)x)[i];
  __hip_bfloat162 p0, p1;
  p0.x = __float2bfloat16(f.x); p0.y = __float2bfloat16(f.y);
  p1.x = __float2bfloat16(f.z); p1.y = __float2bfloat16(f.w);
  ((__hip_bfloat162*)xb)[2*i]   = p0;
  ((__hip_bfloat162*)xb)[2*i+1] = p1;
}

// ---- transpose + cast weights: out[n][c] = in[c][n], bf16 ----
__global__ void wcast_kernel(const float* __restrict__ Wq, const float* __restrict__ Wk,
                             const float* __restrict__ Wv, const float* __restrict__ Wp,
                             __hip_bfloat16* __restrict__ wqkvt, __hip_bfloat16* __restrict__ wpt) {
  __shared__ float tile[32][33];
  int z = blockIdx.z;
  const float* in = (z==0)?Wq:(z==1)?Wk:(z==2)?Wv:Wp;
  __hip_bfloat16* out = (z<3) ? (wqkvt + (size_t)z*N_EMBD*N_EMBD) : wpt;
  int tx = threadIdx.x, ty = threadIdx.y;
  int x  = blockIdx.x*32 + tx;
  int y0 = blockIdx.y*32;
  #pragma unroll
  for (int j=0;j<4;++j) tile[ty + j*8][tx] = in[(size_t)(y0+ty+j*8)*N_EMBD + x];
  __syncthreads();
  int xo  = y0 + tx;
  int yo0 = blockIdx.x*32;
  #pragma unroll
  for (int j=0;j<4;++j)
    out[(size_t)(yo0+ty+j*8)*N_EMBD + xo] = __float2bfloat16(tile[tx][ty+j*8]);
}

// ---- bf16 MFMA GEMM, m97-style: 128x128 tile, BK=64, glds16 staging ----
// LDS layout is XOR-swizzled on the GLOBAL fetch side: physical 16B-group g
// holds logical group g^(row&7)  (glds LDS side must stay linear lane*16).
// mode 0: N=3072 (QKV). Q,K scatter [B,H,T,d]; V stored TRANSPOSED [B,H,d,T]
//   with a per-64-key-tile BIT-PERMUTED column order (R4).
// mode 1: N=1024 (proj), out fp32 = acc + bias.
// R6: (a) XCD-aware block remap: each XCD owns a contiguous bx-chunk so its
//     Bt panel (768KB QKV / 256KB proj) stays L2-resident -> shorter vmcnt
//     drain at the staging barrier (FETCH was 77MB vs 22MB unique = 3.5x
//     refetch from L3/HBM latency). nbx=24/8 both divide by 8 -> bijective.
//     (b) Q/K epilogue via LDS transpose (the proven V pattern): 8 b128
//     global stores replace 64 scalar b16 scatter stores.
__global__ __launch_bounds__(256) void gemm_kernel(
    const __hip_bfloat16* __restrict__ A,   // [M][1024] bf16
    const __hip_bfloat16* __restrict__ Bt,  // [N][1024] bf16 (transposed weight)
    __hip_bfloat16* __restrict__ Qb, __hip_bfloat16* __restrict__ Kb,
    __hip_bfloat16* __restrict__ Vt,        // [B,H,d,T] (key-permuted per 64-tile)
    float* __restrict__ out, const float* __restrict__ bias, int mode) {
  __shared__ __align__(16) char smem[32768];
  __hip_bfloat16* Alin = (__hip_bfloat16*)smem;            // 128x64
  __hip_bfloat16* Blin = (__hip_bfloat16*)(smem + 16384);  // 128x64
  int tid = threadIdx.x;
  // R6a: XCD-chunked remap (dispatch linear id, x fastest; XCD = id%8)
  int wg  = blockIdx.x + gridDim.x*blockIdx.y;
  int per = gridDim.x >> 3;            // bx per XCD (3 for QKV, 1 for proj)
  int xcd = wg & 7, idx = wg >> 3;
  int bxn = xcd*per + (idx % per);
  int byn = idx / per;
  int m0 = byn*128, n0 = bxn*128;
  int w = tid>>6, lane = tid&63, l16 = lane&15, quad = lane>>4;
  int wr = w>>1, wc = w&1;
  int xg = l16 & 7;
  int off0 = ((quad    ) ^ xg)*8;   // physical col offset for logical k-chunk 0
  int off1 = ((quad + 4) ^ xg)*8;   // logical group c*4+quad, c=1
  f32x4 acc[4][4];
  #pragma unroll
  for (int mi=0;mi<4;++mi)
    #pragma unroll
    for (int ni=0;ni<4;++ni) acc[mi][ni] = (f32x4){0.f,0.f,0.f,0.f};

  for (int k0=0; k0<N_EMBD; k0+=64) {
    __syncthreads();   // prev frag reads done before restaging
    #pragma unroll
    for (int rd=0; rd<4; ++rd) {
      int slot = rd*256 + tid;
      int row  = slot>>3;
      int gc8  = ((tid&7) ^ (row&7))*8;
      glds16(A  + (size_t)(m0+row)*N_EMBD + k0 + gc8, Alin + slot*8);
      glds16(Bt + (size_t)(n0+row)*N_EMBD + k0 + gc8, Blin + slot*8);
    }
    __syncthreads();   // drain vmcnt
    #pragma unroll
    for (int c=0;c<2;++c) {
      int off = c ? off1 : off0;
      s16x8 af[4], bfr[4];
      #pragma unroll
      for (int mi=0;mi<4;++mi)
        af[mi] = *(const s16x8*)(Alin + (wr*64+mi*16+l16)*64 + off);
      #pragma unroll
      for (int ni=0;ni<4;++ni)
        bfr[ni] = *(const s16x8*)(Blin + (wc*64+ni*16+l16)*64 + off);
      #pragma unroll
      for (int mi=0;mi<4;++mi)
        #pragma unroll
        for (int ni=0;ni<4;++ni)
          acc[mi][ni] = __builtin_amdgcn_mfma_f32_16x16x32_bf16(af[mi], bfr[ni], acc[mi][ni],0,0,0);
    }
  }

  if (mode == 0) {
    int which = n0 >> 10;
    int bb = m0 >> 11, t0 = m0 & 2047;
    if (which < 2) {
      // R6b: Q/K via LDS transpose, 2 passes over column halves (heads).
      // Tq[128][68]: write banks 2-way (free); 8 b128 coalesced stores/thread.
      __hip_bfloat16* outp = (which==0)?Qb:Kb;
      int hh0 = (n0 & 1023) >> 6;
      __hip_bfloat16 (*Tq)[68] = (__hip_bfloat16(*)[68])smem;  // 128x68x2=17408
      #pragma unroll
      for (int p=0;p<2;++p) {
        __syncthreads();   // smem free (prev frag reads / prev pass stores done)
        if (wc == p) {
          #pragma unroll
          for (int mi=0;mi<4;++mi)
            #pragma unroll
            for (int ni=0;ni<4;++ni) {
              int col = ni*16 + l16;
              int rbase = wr*64 + mi*16 + quad*4;
              #pragma unroll
              for (int r=0;r<4;++r)
                Tq[rbase + r][col] = __float2bfloat16(acc[mi][ni][r]);
            }
        }
        __syncthreads();
        int row = tid>>1, half = (tid&1)*32;
        __hip_bfloat16* dst = outp + ((size_t)(bb*N_HEADS + hh0 + p)*TSEQ + t0 + row)*HD + half;
        #pragma unroll
        for (int c4=0;c4<4;++c4)
          *(uint4*)(dst + c4*8) = *(const uint4*)&Tq[row][half + c4*8];
      }
    } else {
      // V: transpose 128x128 tile (2 heads) in LDS, store [B,H,d,T] with the
      // R4 per-64-tile key permutation baked in: global position p gets key
      // [p5,p2,p4,p3,p1,p0].
      int hh0 = (n0 & 1023) >> 6;
      __hip_bfloat16 (*Ts)[136] = (__hip_bfloat16(*)[136])smem;  // 64x136x2=17408
      #pragma unroll
      for (int p=0;p<2;++p) {
        __syncthreads();   // Ts region free (prev frag reads / prev pass stores done)
        if (wc == p) {
          #pragma unroll
          for (int mi=0;mi<4;++mi)
            #pragma unroll
            for (int ni=0;ni<4;++ni) {
              int dd = ni*16 + l16;
              #pragma unroll
              for (int r=0;r<4;++r)
                Ts[dd][wr*64 + mi*16 + quad*4 + r] = __float2bfloat16(acc[mi][ni][r]);
            }
        }
        __syncthreads();
        int dd = tid>>2, tc = (tid&3)*32;
        __hip_bfloat16* dst = Vt + ((size_t)(bb*N_HEADS + hh0 + p)*HD + dd)*TSEQ + t0;
        #pragma unroll
        for (int pb=0; pb<8; ++pb) {
          int q  = tc + pb*4;          // position within the 128-col block
          int pp = q & 63;             // within-64-tile position (low 2 bits = 0)
          int key = (q & 64) | (pp & 32) | ((pp & 4) << 2) | ((pp & 24) >> 1);
          *(uint2*)(dst + q) = *(const uint2*)&Ts[dd][key];
        }
      }
    }
  } else {
    #pragma unroll
    for (int mi=0;mi<4;++mi) {
      #pragma unroll
      for (int ni=0;ni<4;++ni) {
        int col = n0 + wc*64 + ni*16 + l16;
        float bs = bias[col];
        #pragma unroll
        for (int r=0;r<4;++r) {
          int m = m0 + wr*64 + mi*16 + quad*4 + r;
          out[(size_t)m*N_EMBD + col] = acc[mi][ni][r] + bs;
        }
      }
    }
  }
}

// ---- MFMA causal flash attention, 128 queries/block, 32 q/wave ----
// R0: causal load-balance remap: 137 -> 96us.
// R1: dbuf K/V + counted vmcnt: NULL; kept (harmless).
// R2: raw v_exp_f32: -3us (VALU savings track 1:1 into wall).
// R3: no P LDS round-trip (S^T = mfma(K,Q), in-reg P frags): -9us.
// R4: key-permutation baked into Vt global layout; conflict-free b128 V
//     reads: 86.9 -> 80.7us, conflicts -> 0.
// R5: 1D grid, longest-first sum-equalized perm qb = perm[wgid>>6]:
//     occupancy fix, attn dropped below the gemm dispatches (<75us).
__global__ __launch_bounds__(256) void attn_kernel(
    const __hip_bfloat16* __restrict__ Qb, const __hip_bfloat16* __restrict__ Kb,
    const __hip_bfloat16* __restrict__ Vt, __hip_bfloat16* __restrict__ Yb) {
  __shared__ __align__(16) __hip_bfloat16 Ks[2][64][64];   // [buf][key][d] swizzled
  __shared__ __align__(16) __hip_bfloat16 Vs[2][64][64];   // [buf][d][pos] swizzled
  int tid = threadIdx.x;
  int wgid = blockIdx.x;
  int qb = (int)((0x01237564AB89CDEFull >> ((wgid>>6)*4)) & 15);  // R5 LJF perm
  int h  = (wgid>>2) & 15;
  int b  = wgid & 3;
  int q0 = qb*128;
  size_t bhT  = (size_t)(b*N_HEADS + h)*TSEQ;
  size_t bhHD = (size_t)(b*N_HEADS + h)*HD;
  int lane = tid&63, w = tid>>6, l16 = lane&15, quad = lane>>4;
  int wq = w*32;                       // wave's query band
  int xg = l16 & 7;
  int off0 = ((quad    ) ^ xg)*8;      // logical group quad   (K: d-chunk 0 / V: c=0)
  int off1 = ((quad + 4) ^ xg)*8;      // logical group quad+4 (K: d-chunk 1 / V: c=1)

  // staging addresses (per-thread, constant across tiles except k0)
  int slot0 = tid,        row0 = slot0>>3, gcA = ((tid&7) ^ (row0&7))*8;
  int slot1 = 256 + tid,  row1 = slot1>>3, gcB = ((tid&7) ^ (row1&7))*8;

  // Q fragments for 2 q-tiles x 2 d-chunks (QK^T B-operand)
  s16x8 qf[2][2];
  #pragma unroll
  for (int mi=0;mi<2;++mi) {
    const __hip_bfloat16* qrow = Qb + (bhT + q0 + wq + mi*16 + l16)*HD;
    qf[mi][0] = *(const s16x8*)(qrow + quad*8);
    qf[mi][1] = *(const s16x8*)(qrow + 32 + quad*8);
  }

  f32x4 z4 = {0.f,0.f,0.f,0.f};
  f32x4 oacc[4][2];                    // [d-tile nd][mi], O^T layout
  #pragma unroll
  for (int nd=0;nd<4;++nd) { oacc[nd][0]=z4; oacc[nd][1]=z4; }
  float lsum[2] = {0.f, 0.f};          // per-lane partial row sum (16 keys/tile)

  int ntiles = 2*qb + 2;

  // prologue: stage tile 0 into buffer 0 (4 glds16 per thread)
  {
    glds16(Kb + (bhT + 0 + row0)*HD + gcA,    &Ks[0][0][0] + slot0*8);
    glds16(Vt + (bhHD + row0)*TSEQ + 0 + gcA, &Vs[0][0][0] + slot0*8);
    glds16(Kb + (bhT + 0 + row1)*HD + gcB,    &Ks[0][0][0] + slot1*8);
    glds16(Vt + (bhHD + row1)*TSEQ + 0 + gcB, &Vs[0][0][0] + slot1*8);
  }

  for (int t=0; t<ntiles; ++t) {
    int cur = t&1;
    int k0 = t*64;
    // A: issue next tile's staging into the other buffer
    if (t+1 < ntiles) {
      int kn = k0 + 64;
      glds16(Kb + (bhT + kn + row0)*HD + gcA,     &Ks[cur^1][0][0] + slot0*8);
      glds16(Vt + (bhHD + row0)*TSEQ + kn + gcA,  &Vs[cur^1][0][0] + slot0*8);
      glds16(Kb + (bhT + kn + row1)*HD + gcB,     &Ks[cur^1][0][0] + slot1*8);
      glds16(Vt + (bhHD + row1)*TSEQ + kn + gcB,  &Vs[cur^1][0][0] + slot1*8);
      asm volatile("s_waitcnt vmcnt(4)" ::: "memory");
    } else {
      asm volatile("s_waitcnt vmcnt(0)" ::: "memory");
    }
    // C: all waves' cur-buffer loads landed
    __builtin_amdgcn_s_barrier();
    __builtin_amdgcn_sched_barrier(0);

    const __hip_bfloat16* Kc = &Ks[cur][0][0];
    const __hip_bfloat16* Vc = &Vs[cur][0][0];

    // S^T = K Q^T : per wave 64key x 32q.  sacc[ni][mi]: lane holds
    // S^T[key=16ni+4quad+r][q=l16 (+16mi)]
    f32x4 sacc[4][2];
    #pragma unroll
    for (int ni=0; ni<4; ++ni) {
      s16x8 kb0 = *(const s16x8*)(Kc + (ni*16+l16)*64 + off0);
      s16x8 kb1 = *(const s16x8*)(Kc + (ni*16+l16)*64 + off1);
      #pragma unroll
      for (int mi=0; mi<2; ++mi) {
        f32x4 s = z4;
        s = __builtin_amdgcn_mfma_f32_16x16x32_bf16(kb0, qf[mi][0], s,0,0,0);
        s = __builtin_amdgcn_mfma_f32_16x16x32_bf16(kb1, qf[mi][1], s,0,0,0);
        sacc[ni][mi] = s;
      }
    }

    // mask + exp; accumulate lsum; pack P pairs in-register (no LDS)
    unsigned pkw[2][4][2];   // [mi][ni][r-pair]: keys 16ni+4quad+{2p,2p+1}
    if (q0 + wq >= k0 + 63) {
      #pragma unroll
      for (int ni=0; ni<4; ++ni) {
        #pragma unroll
        for (int mi=0; mi<2; ++mi) {
          float e0 = exp_scaled(sacc[ni][mi][0]);
          float e1 = exp_scaled(sacc[ni][mi][1]);
          float e2 = exp_scaled(sacc[ni][mi][2]);
          float e3 = exp_scaled(sacc[ni][mi][3]);
          lsum[mi] += (e0+e1)+(e2+e3);
          pkw[mi][ni][0] = cvtpk(e0, e1);
          pkw[mi][ni][1] = cvtpk(e2, e3);
        }
      }
    } else {
      #pragma unroll
      for (int ni=0; ni<4; ++ni) {
        int kbase = k0 + ni*16 + quad*4;
        #pragma unroll
        for (int mi=0; mi<2; ++mi) {
          int qrow = q0 + wq + mi*16 + l16;
          float e0 = (qrow >= kbase    ) ? exp_scaled(sacc[ni][mi][0]) : 0.f;
          float e1 = (qrow >= kbase + 1) ? exp_scaled(sacc[ni][mi][1]) : 0.f;
          float e2 = (qrow >= kbase + 2) ? exp_scaled(sacc[ni][mi][2]) : 0.f;
          float e3 = (qrow >= kbase + 3) ? exp_scaled(sacc[ni][mi][3]) : 0.f;
          lsum[mi] += (e0+e1)+(e2+e3);
          pkw[mi][ni][0] = cvtpk(e0, e1);
          pkw[mi][ni][1] = cvtpk(e2, e3);
        }
      }
    }

    // O^T += V^T P^T : A = V-frag (b128, K-read pattern on permuted Vt),
    // B = P-frag (in regs).  k-slot (c,quad,j) <-> key 32c+16(j>>2)+4quad+(j&3)
    // on BOTH operands by construction.
    union U8 { s16x8 v; unsigned u[4]; };
    U8 pf[2][2];   // [c][mi]
    #pragma unroll
    for (int c=0; c<2; ++c)
      #pragma unroll
      for (int mi=0; mi<2; ++mi) {
        pf[c][mi].u[0] = pkw[mi][2*c  ][0];
        pf[c][mi].u[1] = pkw[mi][2*c  ][1];
        pf[c][mi].u[2] = pkw[mi][2*c+1][0];
        pf[c][mi].u[3] = pkw[mi][2*c+1][1];
      }
    #pragma unroll
    for (int nd=0; nd<4; ++nd) {
      const __hip_bfloat16* vrow = Vc + (nd*16 + l16)*64;
      s16x8 vb0 = *(const s16x8*)(vrow + off0);
      s16x8 vb1 = *(const s16x8*)(vrow + off1);
      oacc[nd][0] = __builtin_amdgcn_mfma_f32_16x16x32_bf16(vb0, pf[0][0].v, oacc[nd][0],0,0,0);
      oacc[nd][1] = __builtin_amdgcn_mfma_f32_16x16x32_bf16(vb0, pf[0][1].v, oacc[nd][1],0,0,0);
      oacc[nd][0] = __builtin_amdgcn_mfma_f32_16x16x32_bf16(vb1, pf[1][0].v, oacc[nd][0],0,0,0);
      oacc[nd][1] = __builtin_amdgcn_mfma_f32_16x16x32_bf16(vb1, pf[1][1].v, oacc[nd][1],0,0,0);
    }

    // E: all frag reads of buf[cur] complete -> safe to restage it next iter
    asm volatile("s_waitcnt lgkmcnt(0)" ::: "memory");
    __builtin_amdgcn_s_barrier();
    __builtin_amdgcn_sched_barrier(0);
  }

  // reduce lsum across the 4 lanes sharing l16 (quads)
  #pragma unroll
  for (int mi=0; mi<2; ++mi) {
    lsum[mi] += __shfl_xor(lsum[mi], 16);
    lsum[mi] += __shfl_xor(lsum[mi], 32);
  }

  // epilogue: lane holds O^T[d=16nd+4quad+r][q=l16+16mi]; pack 4 d-values
  // (8B) per (nd,mi) and store.
  #pragma unroll
  for (int mi=0; mi<2; ++mi) {
    float inv = 1.f / lsum[mi];
    int tq = q0 + wq + mi*16 + l16;
    __hip_bfloat16* yr = Yb + ((size_t)(b*TSEQ + tq))*N_EMBD + h*HD + quad*4;
    #pragma unroll
    for (int nd=0; nd<4; ++nd) {
      uint2 o;
      o.x = cvtpk(oacc[nd][mi][0]*inv, oacc[nd][mi][1]*inv);
      o.y = cvtpk(oacc[nd][mi][2]*inv, oacc[nd][mi][3]*inv);
      *(uint2*)(yr + nd*16) = o;
    }
  }
}

extern "C" void kernel_launch(void* const* d_in, const int* in_sizes, int n_in,
                              void* d_out, int out_size, void* d_ws, size_t ws_size,
                              hipStream_t stream) {
  const float* x  = (const float*)d_in[0];
  const float* Wq = (const float*)d_in[1];
  const float* Wk = (const float*)d_in[2];
  const float* Wv = (const float*)d_in[3];
  const float* Wp = (const float*)d_in[4];
  const float* bp = (const float*)d_in[5];

  char* w = (char*)d_ws;
  __hip_bfloat16* xb    = (__hip_bfloat16*)w;  w += (size_t)M_TOT*N_EMBD*2;   // 16 MB
  __hip_bfloat16* wqkvt = (__hip_bfloat16*)w;  w += (size_t)3*N_EMBD*N_EMBD*2;// 6 MB
  __hip_bfloat16* wpt   = (__hip_bfloat16*)w;  w += (size_t)N_EMBD*N_EMBD*2;  // 2 MB
  __hip_bfloat16* Qb    = (__hip_bfloat16*)w;  w += (size_t)M_TOT*N_EMBD*2;   // 16 MB
  __hip_bfloat16* Kb    = (__hip_bfloat16*)w;  w += (size_t)M_TOT*N_EMBD*2;   // 16 MB
  __hip_bfloat16* Vt    = (__hip_bfloat16*)w;  w += (size_t)M_TOT*N_EMBD*2;   // 16 MB [B,H,d,T] permuted
  __hip_bfloat16* Yb    = (__hip_bfloat16*)w;                                  // 16 MB (88 MB total)

  xcast_kernel<<<dim3(M_TOT*N_EMBD/1024), dim3(256), 0, stream>>>(x, xb);
  wcast_kernel<<<dim3(32,32,4), dim3(32,8), 0, stream>>>(Wq,Wk,Wv,Wp,wqkvt,wpt);
  gemm_kernel<<<dim3(24,64), dim3(256), 0, stream>>>(xb, wqkvt, Qb,Kb,Vt, nullptr, nullptr, 0);
  attn_kernel<<<dim3(1024), dim3(256), 0, stream>>>(Qb,Kb,Vt,Yb);
  gemm_kernel<<<dim3(8,64), dim3(256), 0, stream>>>(Yb, wpt, nullptr,nullptr,nullptr,
                                                    (float*)d_out, bp, 1);
}

// Round 8
// 243.886 us; speedup vs baseline: 1.0091x; 1.0091x over previous
//
#include <hip/hip_runtime.h>
#include <hip/hip_bf16.h>

#define N_EMBD 1024
#define N_HEADS 16
#define HD 64
#define TSEQ 2048
#define BATCH 4
#define M_TOT (BATCH*TSEQ)   // 8192

typedef short s16x8 __attribute__((ext_vector_type(8)));
typedef float f32x4 __attribute__((ext_vector_type(4)));

__device__ __forceinline__ void glds16(const void* g, void* l) {
  __builtin_amdgcn_global_load_lds((const __attribute__((address_space(1))) void*)g,
                                   (__attribute__((address_space(3))) void*)l, 16, 0, 0);
}

// exp(s*0.125) = 2^(s * 0.125*log2(e)) via a single hardware v_exp_f32 (R2).
__device__ __forceinline__ float exp_scaled(float s) {
  float r;
  asm("v_exp_f32 %0, %1\n\ts_nop 0" : "=v"(r) : "v"(s * 0.18033688011112042f));
  return r;
}

// pack two f32 -> bf16x2 (src0 in low 16). No builtin on gfx950 (T12/m240).
__device__ __forceinline__ unsigned cvtpk(float lo, float hi) {
  unsigned r;
  asm("v_cvt_pk_bf16_f32 %0, %1, %2" : "=v"(r) : "v"(lo), "v"(hi));
  return r;
}

// ---- cast x fp32 -> bf16, 4 elems/thread ----
__global__ __launch_bounds__(256) void xcast_kernel(const float* __restrict__ x,
                                                    __hip_bfloat16* __restrict__ xb) {
  int i = blockIdx.x * 256 + threadIdx.x;
  float4 f = ((const float4*)x)[i];
  __hip_bfloat162 p0, p1;
  p0.x = __float2bfloat16(f.x); p0.y = __float2bfloat16(f.y);
  p1.x = __float2bfloat16(f.z); p1.y = __float2bfloat16(f.w);
  ((__hip_bfloat162*)xb)[2*i]   = p0;
  ((__hip_bfloat162*)xb)[2*i+1] = p1;
}

// ---- transpose + cast weights: out[n][c] = in[c][n], bf16 ----
__global__ void wcast_kernel(const float* __restrict__ Wq, const float* __restrict__ Wk,
                             const float* __restrict__ Wv, const float* __restrict__ Wp,
                             __hip_bfloat16* __restrict__ wqkvt, __hip_bfloat16* __restrict__ wpt) {
  __shared__ float tile[32][33];
  int z = blockIdx.z;
  const float* in = (z==0)?Wq:(z==1)?Wk:(z==2)?Wv:Wp;
  __hip_bfloat16* out = (z<3) ? (wqkvt + (size_t)z*N_EMBD*N_EMBD) : wpt;
  int tx = threadIdx.x, ty = threadIdx.y;
  int x  = blockIdx.x*32 + tx;
  int y0 = blockIdx.y*32;
  #pragma unroll
  for (int j=0;j<4;++j) tile[ty + j*8][tx] = in[(size_t)(y0+ty+j*8)*N_EMBD + x];
  __syncthreads();
  int xo  = y0 + tx;
  int yo0 = blockIdx.x*32;
  #pragma unroll
  for (int j=0;j<4;++j)
    out[(size_t)(yo0+ty+j*8)*N_EMBD + xo] = __float2bfloat16(tile[tx][ty+j*8]);
}

// ---- bf16 MFMA GEMM, m97-style: 128x128 tile, BK=64, glds16 staging ----
// LDS layout is XOR-swizzled on the GLOBAL fetch side: physical 16B-group g
// holds logical group g^(row&7)  (glds LDS side must stay linear lane*16).
// mode 0: N=3072 (QKV). Q,K scatter [B,H,T,d]; V stored TRANSPOSED [B,H,d,T]
//   with a per-64-key-tile BIT-PERMUTED column order (R4).
// mode 1: N=1024 (proj), out fp32 = acc + bias.
// R6 POST-MORTEM (reverted): XCD remap left FETCH_SIZE bit-identical
// (76.86MB) -> dispatch/L2 model wrong; bundled LDS-transpose Q/K epilogue
// +4 barriers regressed QKV 75->81.4us. Both reverted. QKV at 687 TF is at
// the m97-structure ceiling for this K=1024 shape (m102 shape curve).
__global__ __launch_bounds__(256) void gemm_kernel(
    const __hip_bfloat16* __restrict__ A,   // [M][1024] bf16
    const __hip_bfloat16* __restrict__ Bt,  // [N][1024] bf16 (transposed weight)
    __hip_bfloat16* __restrict__ Qb, __hip_bfloat16* __restrict__ Kb,
    __hip_bfloat16* __restrict__ Vt,        // [B,H,d,T] (key-permuted per 64-tile)
    float* __restrict__ out, const float* __restrict__ bias, int mode) {
  __shared__ __align__(16) char smem[32768];
  __hip_bfloat16* Alin = (__hip_bfloat16*)smem;            // 128x64
  __hip_bfloat16* Blin = (__hip_bfloat16*)(smem + 16384);  // 128x64
  int tid = threadIdx.x;
  int m0 = blockIdx.y*128, n0 = blockIdx.x*128;
  int w = tid>>6, lane = tid&63, l16 = lane&15, quad = lane>>4;
  int wr = w>>1, wc = w&1;
  int xg = l16 & 7;
  int off0 = ((quad    ) ^ xg)*8;   // physical col offset for logical k-chunk 0
  int off1 = ((quad + 4) ^ xg)*8;   // logical group c*4+quad, c=1
  f32x4 acc[4][4];
  #pragma unroll
  for (int mi=0;mi<4;++mi)
    #pragma unroll
    for (int ni=0;ni<4;++ni) acc[mi][ni] = (f32x4){0.f,0.f,0.f,0.f};

  for (int k0=0; k0<N_EMBD; k0+=64) {
    __syncthreads();   // prev frag reads done before restaging
    #pragma unroll
    for (int rd=0; rd<4; ++rd) {
      int slot = rd*256 + tid;
      int row  = slot>>3;
      int gc8  = ((tid&7) ^ (row&7))*8;
      glds16(A  + (size_t)(m0+row)*N_EMBD + k0 + gc8, Alin + slot*8);
      glds16(Bt + (size_t)(n0+row)*N_EMBD + k0 + gc8, Blin + slot*8);
    }
    __syncthreads();   // drain vmcnt
    #pragma unroll
    for (int c=0;c<2;++c) {
      int off = c ? off1 : off0;
      s16x8 af[4], bfr[4];
      #pragma unroll
      for (int mi=0;mi<4;++mi)
        af[mi] = *(const s16x8*)(Alin + (wr*64+mi*16+l16)*64 + off);
      #pragma unroll
      for (int ni=0;ni<4;++ni)
        bfr[ni] = *(const s16x8*)(Blin + (wc*64+ni*16+l16)*64 + off);
      #pragma unroll
      for (int mi=0;mi<4;++mi)
        #pragma unroll
        for (int ni=0;ni<4;++ni)
          acc[mi][ni] = __builtin_amdgcn_mfma_f32_16x16x32_bf16(af[mi], bfr[ni], acc[mi][ni],0,0,0);
    }
  }

  if (mode == 0) {
    int which = n0 >> 10;
    int bb = m0 >> 11, t0 = m0 & 2047;
    if (which < 2) {
      __hip_bfloat16* outp = (which==0)?Qb:Kb;
      #pragma unroll
      for (int mi=0;mi<4;++mi) {
        #pragma unroll
        for (int ni=0;ni<4;++ni) {
          int ncol = (n0 & 1023) + wc*64 + ni*16 + l16;
          int hh = ncol>>6, dd = ncol&63;
          #pragma unroll
          for (int r=0;r<4;++r) {
            int t = t0 + wr*64 + mi*16 + quad*4 + r;
            outp[((size_t)(bb*N_HEADS + hh)*TSEQ + t)*HD + dd] = __float2bfloat16(acc[mi][ni][r]);
          }
        }
      }
    } else {
      // V: transpose 128x128 tile (2 heads) in LDS, store [B,H,d,T] with the
      // R4 per-64-tile key permutation baked in: global position p gets key
      // [p5,p2,p4,p3,p1,p0].
      int hh0 = (n0 & 1023) >> 6;
      __hip_bfloat16 (*Ts)[136] = (__hip_bfloat16(*)[136])smem;  // 64x136x2=17408
      #pragma unroll
      for (int p=0;p<2;++p) {
        __syncthreads();   // Ts region free (prev frag reads / prev pass stores done)
        if (wc == p) {
          #pragma unroll
          for (int mi=0;mi<4;++mi)
            #pragma unroll
            for (int ni=0;ni<4;++ni) {
              int dd = ni*16 + l16;
              #pragma unroll
              for (int r=0;r<4;++r)
                Ts[dd][wr*64 + mi*16 + quad*4 + r] = __float2bfloat16(acc[mi][ni][r]);
            }
        }
        __syncthreads();
        int dd = tid>>2, tc = (tid&3)*32;
        __hip_bfloat16* dst = Vt + ((size_t)(bb*N_HEADS + hh0 + p)*HD + dd)*TSEQ + t0;
        #pragma unroll
        for (int pb=0; pb<8; ++pb) {
          int q  = tc + pb*4;          // position within the 128-col block
          int pp = q & 63;             // within-64-tile position (low 2 bits = 0)
          int key = (q & 64) | (pp & 32) | ((pp & 4) << 2) | ((pp & 24) >> 1);
          *(uint2*)(dst + q) = *(const uint2*)&Ts[dd][key];
        }
      }
    }
  } else {
    #pragma unroll
    for (int mi=0;mi<4;++mi) {
      #pragma unroll
      for (int ni=0;ni<4;++ni) {
        int col = n0 + wc*64 + ni*16 + l16;
        float bs = bias[col];
        #pragma unroll
        for (int r=0;r<4;++r) {
          int m = m0 + wr*64 + mi*16 + quad*4 + r;
          out[(size_t)m*N_EMBD + col] = acc[mi][ni][r] + bs;
        }
      }
    }
  }
}

// ---- MFMA causal flash attention, 128 queries/block, 32 q/wave ----
// R0: causal load-balance remap: 137 -> 96us.
// R1: dbuf K/V + counted vmcnt: NULL; kept (harmless).
// R2: raw v_exp_f32: -3us (VALU savings track 1:1 into wall).
// R3: no P LDS round-trip (S^T = mfma(K,Q), in-reg P frags): -9us.
// R4: key-permutation baked into Vt global layout; conflict-free b128 V
//     reads: 86.9 -> 80.7us, conflicts -> 0.
// R5: 1D grid, longest-first sum-equalized perm qb = perm[wgid>>6]:
//     occupancy fix, attn dropped below the gemm dispatches (<75us).
// R7 (this round): T5 s_setprio(1)/(0) around the QK^T and PV MFMA
//     clusters. Prereq per m191: co-resident blocks at DIFFERENT phases
//     (ours: independent blocks, desynced ntiles via R5 perm) -> the CU
//     scheduler can prefer MFMA-entering waves over other blocks'
//     staging/exp waves. NOT applied to gemm (m190: null/negative on
//     lockstep GEMM).
__global__ __launch_bounds__(256) void attn_kernel(
    const __hip_bfloat16* __restrict__ Qb, const __hip_bfloat16* __restrict__ Kb,
    const __hip_bfloat16* __restrict__ Vt, __hip_bfloat16* __restrict__ Yb) {
  __shared__ __align__(16) __hip_bfloat16 Ks[2][64][64];   // [buf][key][d] swizzled
  __shared__ __align__(16) __hip_bfloat16 Vs[2][64][64];   // [buf][d][pos] swizzled
  int tid = threadIdx.x;
  int wgid = blockIdx.x;
  int qb = (int)((0x01237564AB89CDEFull >> ((wgid>>6)*4)) & 15);  // R5 LJF perm
  int h  = (wgid>>2) & 15;
  int b  = wgid & 3;
  int q0 = qb*128;
  size_t bhT  = (size_t)(b*N_HEADS + h)*TSEQ;
  size_t bhHD = (size_t)(b*N_HEADS + h)*HD;
  int lane = tid&63, w = tid>>6, l16 = lane&15, quad = lane>>4;
  int wq = w*32;                       // wave's query band
  int xg = l16 & 7;
  int off0 = ((quad    ) ^ xg)*8;      // logical group quad   (K: d-chunk 0 / V: c=0)
  int off1 = ((quad + 4) ^ xg)*8;      // logical group quad+4 (K: d-chunk 1 / V: c=1)

  // staging addresses (per-thread, constant across tiles except k0)
  int slot0 = tid,        row0 = slot0>>3, gcA = ((tid&7) ^ (row0&7))*8;
  int slot1 = 256 + tid,  row1 = slot1>>3, gcB = ((tid&7) ^ (row1&7))*8;

  // Q fragments for 2 q-tiles x 2 d-chunks (QK^T B-operand)
  s16x8 qf[2][2];
  #pragma unroll
  for (int mi=0;mi<2;++mi) {
    const __hip_bfloat16* qrow = Qb + (bhT + q0 + wq + mi*16 + l16)*HD;
    qf[mi][0] = *(const s16x8*)(qrow + quad*8);
    qf[mi][1] = *(const s16x8*)(qrow + 32 + quad*8);
  }

  f32x4 z4 = {0.f,0.f,0.f,0.f};
  f32x4 oacc[4][2];                    // [d-tile nd][mi], O^T layout
  #pragma unroll
  for (int nd=0;nd<4;++nd) { oacc[nd][0]=z4; oacc[nd][1]=z4; }
  float lsum[2] = {0.f, 0.f};          // per-lane partial row sum (16 keys/tile)

  int ntiles = 2*qb + 2;

  // prologue: stage tile 0 into buffer 0 (4 glds16 per thread)
  {
    glds16(Kb + (bhT + 0 + row0)*HD + gcA,    &Ks[0][0][0] + slot0*8);
    glds16(Vt + (bhHD + row0)*TSEQ + 0 + gcA, &Vs[0][0][0] + slot0*8);
    glds16(Kb + (bhT + 0 + row1)*HD + gcB,    &Ks[0][0][0] + slot1*8);
    glds16(Vt + (bhHD + row1)*TSEQ + 0 + gcB, &Vs[0][0][0] + slot1*8);
  }

  for (int t=0; t<ntiles; ++t) {
    int cur = t&1;
    int k0 = t*64;
    // A: issue next tile's staging into the other buffer
    if (t+1 < ntiles) {
      int kn = k0 + 64;
      glds16(Kb + (bhT + kn + row0)*HD + gcA,     &Ks[cur^1][0][0] + slot0*8);
      glds16(Vt + (bhHD + row0)*TSEQ + kn + gcA,  &Vs[cur^1][0][0] + slot0*8);
      glds16(Kb + (bhT + kn + row1)*HD + gcB,     &Ks[cur^1][0][0] + slot1*8);
      glds16(Vt + (bhHD + row1)*TSEQ + kn + gcB,  &Vs[cur^1][0][0] + slot1*8);
      asm volatile("s_waitcnt vmcnt(4)" ::: "memory");
    } else {
      asm volatile("s_waitcnt vmcnt(0)" ::: "memory");
    }
    // C: all waves' cur-buffer loads landed
    __builtin_amdgcn_s_barrier();
    __builtin_amdgcn_sched_barrier(0);

    const __hip_bfloat16* Kc = &Ks[cur][0][0];
    const __hip_bfloat16* Vc = &Vs[cur][0][0];

    // S^T = K Q^T : per wave 64key x 32q.  sacc[ni][mi]: lane holds
    // S^T[key=16ni+4quad+r][q=l16 (+16mi)]
    f32x4 sacc[4][2];
    __builtin_amdgcn_s_setprio(1);     // R7: favor MFMA wave on the CU
    #pragma unroll
    for (int ni=0; ni<4; ++ni) {
      s16x8 kb0 = *(const s16x8*)(Kc + (ni*16+l16)*64 + off0);
      s16x8 kb1 = *(const s16x8*)(Kc + (ni*16+l16)*64 + off1);
      #pragma unroll
      for (int mi=0; mi<2; ++mi) {
        f32x4 s = z4;
        s = __builtin_amdgcn_mfma_f32_16x16x32_bf16(kb0, qf[mi][0], s,0,0,0);
        s = __builtin_amdgcn_mfma_f32_16x16x32_bf16(kb1, qf[mi][1], s,0,0,0);
        sacc[ni][mi] = s;
      }
    }
    __builtin_amdgcn_s_setprio(0);

    // mask + exp; accumulate lsum; pack P pairs in-register (no LDS)
    unsigned pkw[2][4][2];   // [mi][ni][r-pair]: keys 16ni+4quad+{2p,2p+1}
    if (q0 + wq >= k0 + 63) {
      #pragma unroll
      for (int ni=0; ni<4; ++ni) {
        #pragma unroll
        for (int mi=0; mi<2; ++mi) {
          float e0 = exp_scaled(sacc[ni][mi][0]);
          float e1 = exp_scaled(sacc[ni][mi][1]);
          float e2 = exp_scaled(sacc[ni][mi][2]);
          float e3 = exp_scaled(sacc[ni][mi][3]);
          lsum[mi] += (e0+e1)+(e2+e3);
          pkw[mi][ni][0] = cvtpk(e0, e1);
          pkw[mi][ni][1] = cvtpk(e2, e3);
        }
      }
    } else {
      #pragma unroll
      for (int ni=0; ni<4; ++ni) {
        int kbase = k0 + ni*16 + quad*4;
        #pragma unroll
        for (int mi=0; mi<2; ++mi) {
          int qrow = q0 + wq + mi*16 + l16;
          float e0 = (qrow >= kbase    ) ? exp_scaled(sacc[ni][mi][0]) : 0.f;
          float e1 = (qrow >= kbase + 1) ? exp_scaled(sacc[ni][mi][1]) : 0.f;
          float e2 = (qrow >= kbase + 2) ? exp_scaled(sacc[ni][mi][2]) : 0.f;
          float e3 = (qrow >= kbase + 3) ? exp_scaled(sacc[ni][mi][3]) : 0.f;
          lsum[mi] += (e0+e1)+(e2+e3);
          pkw[mi][ni][0] = cvtpk(e0, e1);
          pkw[mi][ni][1] = cvtpk(e2, e3);
        }
      }
    }

    // O^T += V^T P^T : A = V-frag (b128, K-read pattern on permuted Vt),
    // B = P-frag (in regs).  k-slot (c,quad,j) <-> key 32c+16(j>>2)+4quad+(j&3)
    // on BOTH operands by construction.
    union U8 { s16x8 v; unsigned u[4]; };
    U8 pf[2][2];   // [c][mi]
    #pragma unroll
    for (int c=0; c<2; ++c)
      #pragma unroll
      for (int mi=0; mi<2; ++mi) {
        pf[c][mi].u[0] = pkw[mi][2*c  ][0];
        pf[c][mi].u[1] = pkw[mi][2*c  ][1];
        pf[c][mi].u[2] = pkw[mi][2*c+1][0];
        pf[c][mi].u[3] = pkw[mi][2*c+1][1];
      }
    __builtin_amdgcn_s_setprio(1);     // R7: favor MFMA wave on the CU
    #pragma unroll
    for (int nd=0; nd<4; ++nd) {
      const __hip_bfloat16* vrow = Vc + (nd*16 + l16)*64;
      s16x8 vb0 = *(const s16x8*)(vrow + off0);
      s16x8 vb1 = *(const s16x8*)(vrow + off1);
      oacc[nd][0] = __builtin_amdgcn_mfma_f32_16x16x32_bf16(vb0, pf[0][0].v, oacc[nd][0],0,0,0);
      oacc[nd][1] = __builtin_amdgcn_mfma_f32_16x16x32_bf16(vb0, pf[0][1].v, oacc[nd][1],0,0,0);
      oacc[nd][0] = __builtin_amdgcn_mfma_f32_16x16x32_bf16(vb1, pf[1][0].v, oacc[nd][0],0,0,0);
      oacc[nd][1] = __builtin_amdgcn_mfma_f32_16x16x32_bf16(vb1, pf[1][1].v, oacc[nd][1],0,0,0);
    }
    __builtin_amdgcn_s_setprio(0);

    // E: all frag reads of buf[cur] complete -> safe to restage it next iter
    asm volatile("s_waitcnt lgkmcnt(0)" ::: "memory");
    __builtin_amdgcn_s_barrier();
    __builtin_amdgcn_sched_barrier(0);
  }

  // reduce lsum across the 4 lanes sharing l16 (quads)
  #pragma unroll
  for (int mi=0; mi<2; ++mi) {
    lsum[mi] += __shfl_xor(lsum[mi], 16);
    lsum[mi] += __shfl_xor(lsum[mi], 32);
  }

  // epilogue: lane holds O^T[d=16nd+4quad+r][q=l16+16mi]; pack 4 d-values
  // (8B) per (nd,mi) and store.
  #pragma unroll
  for (int mi=0; mi<2; ++mi) {
    float inv = 1.f / lsum[mi];
    int tq = q0 + wq + mi*16 + l16;
    __hip_bfloat16* yr = Yb + ((size_t)(b*TSEQ + tq))*N_EMBD + h*HD + quad*4;
    #pragma unroll
    for (int nd=0; nd<4; ++nd) {
      uint2 o;
      o.x = cvtpk(oacc[nd][mi][0]*inv, oacc[nd][mi][1]*inv);
      o.y = cvtpk(oacc[nd][mi][2]*inv, oacc[nd][mi][3]*inv);
      *(uint2*)(yr + nd*16) = o;
    }
  }
}

extern "C" void kernel_launch(void* const* d_in, const int* in_sizes, int n_in,
                              void* d_out, int out_size, void* d_ws, size_t ws_size,
                              hipStream_t stream) {
  const float* x  = (const float*)d_in[0];
  const float* Wq = (const float*)d_in[1];
  const float* Wk = (const float*)d_in[2];
  const float* Wv = (const float*)d_in[3];
  const float* Wp = (const float*)d_in[4];
  const float* bp = (const float*)d_in[5];

  char* w = (char*)d_ws;
  __hip_bfloat16* xb    = (__hip_bfloat16*)w;  w += (size_t)M_TOT*N_EMBD*2;   // 16 MB
  __hip_bfloat16* wqkvt = (__hip_bfloat16*)w;  w += (size_t)3*N_EMBD*N_EMBD*2;// 6 MB
  __hip_bfloat16* wpt   = (__hip_bfloat16*)w;  w += (size_t)N_EMBD*N_EMBD*2;  // 2 MB
  __hip_bfloat16* Qb    = (__hip_bfloat16*)w;  w += (size_t)M_TOT*N_EMBD*2;   // 16 MB
  __hip_bfloat16* Kb    = (__hip_bfloat16*)w;  w += (size_t)M_TOT*N_EMBD*2;   // 16 MB
  __hip_bfloat16* Vt    = (__hip_bfloat16*)w;  w += (size_t)M_TOT*N_EMBD*2;   // 16 MB [B,H,d,T] permuted
  __hip_bfloat16* Yb    = (__hip_bfloat16*)w;                                  // 16 MB (88 MB total)

  xcast_kernel<<<dim3(M_TOT*N_EMBD/1024), dim3(256), 0, stream>>>(x, xb);
  wcast_kernel<<<dim3(32,32,4), dim3(32,8), 0, stream>>>(Wq,Wk,Wv,Wp,wqkvt,wpt);
  gemm_kernel<<<dim3(24,64), dim3(256), 0, stream>>>(xb, wqkvt, Qb,Kb,Vt, nullptr, nullptr, 0);
  attn_kernel<<<dim3(1024), dim3(256), 0, stream>>>(Qb,Kb,Vt,Yb);
  gemm_kernel<<<dim3(8,64), dim3(256), 0, stream>>>(Yb, wpt, nullptr,nullptr,nullptr,
                                                    (float*)d_out, bp, 1);
}

// Round 9
// 238.489 us; speedup vs baseline: 1.0320x; 1.0226x over previous
//
#include <hip/hip_runtime.h>
#include <hip/hip_bf16.h>

#define N_EMBD 1024
#define N_HEADS 16
#define HD 64
#define TSEQ 2048
#define BATCH 4
#define M_TOT (BATCH*TSEQ)   // 8192

typedef short s16x8 __attribute__((ext_vector_type(8)));
typedef float f32x4 __attribute__((ext_vector_type(4)));

__device__ __forceinline__ void glds16(const void* g, void* l) {
  __builtin_amdgcn_global_load_lds((const __attribute__((address_space(1))) void*)g,
                                   (__attribute__((address_space(3))) void*)l, 16, 0, 0);
}

// exp(s*0.125) = 2^(s * 0.125*log2(e)) via a single hardware v_exp_f32 (R2).
__device__ __forceinline__ float exp_scaled(float s) {
  float r;
  asm("v_exp_f32 %0, %1\n\ts_nop 0" : "=v"(r) : "v"(s * 0.18033688011112042f));
  return r;
}

// pack two f32 -> bf16x2 (src0 in low 16). No builtin on gfx950 (T12/m240).
__device__ __forceinline__ unsigned cvtpk(float lo, float hi) {
  unsigned r;
  asm("v_cvt_pk_bf16_f32 %0, %1, %2" : "=v"(r) : "v"(lo), "v"(hi));
  return r;
}

// ---- cast x fp32 -> bf16, 4 elems/thread ----
__global__ __launch_bounds__(256) void xcast_kernel(const float* __restrict__ x,
                                                    __hip_bfloat16* __restrict__ xb) {
  int i = blockIdx.x * 256 + threadIdx.x;
  float4 f = ((const float4*)x)[i];
  __hip_bfloat162 p0, p1;
  p0.x = __float2bfloat16(f.x); p0.y = __float2bfloat16(f.y);
  p1.x = __float2bfloat16(f.z); p1.y = __float2bfloat16(f.w);
  ((__hip_bfloat162*)xb)[2*i]   = p0;
  ((__hip_bfloat162*)xb)[2*i+1] = p1;
}

// ---- transpose + cast weights: out[n][c] = in[c][n], bf16 ----
__global__ void wcast_kernel(const float* __restrict__ Wq, const float* __restrict__ Wk,
                             const float* __restrict__ Wv, const float* __restrict__ Wp,
                             __hip_bfloat16* __restrict__ wqkvt, __hip_bfloat16* __restrict__ wpt) {
  __shared__ float tile[32][33];
  int z = blockIdx.z;
  const float* in = (z==0)?Wq:(z==1)?Wk:(z==2)?Wv:Wp;
  __hip_bfloat16* out = (z<3) ? (wqkvt + (size_t)z*N_EMBD*N_EMBD) : wpt;
  int tx = threadIdx.x, ty = threadIdx.y;
  int x  = blockIdx.x*32 + tx;
  int y0 = blockIdx.y*32;
  #pragma unroll
  for (int j=0;j<4;++j) tile[ty + j*8][tx] = in[(size_t)(y0+ty+j*8)*N_EMBD + x];
  __syncthreads();
  int xo  = y0 + tx;
  int yo0 = blockIdx.x*32;
  #pragma unroll
  for (int j=0;j<4;++j)
    out[(size_t)(yo0+ty+j*8)*N_EMBD + xo] = __float2bfloat16(tile[tx][ty+j*8]);
}

// ================= R8: 256x256 8-phase QKV GEMM =================
// m97 2-barrier structure measured 687 TF (26% MfmaUtil) = its documented
// ceiling at K=1024. This is the T3+T4+T5 8-phase schedule (catalog:
// 1563 TF verified at 256p tile, BK=64):
//  - 512 thr = 8 waves; per-wave 64x32 sub-tile of EACH 128x128 C-quadrant.
//  - LDS 128KB: dbuf x (A 256x64 + B 256x64). Halves = 128 rows.
//  - Halves of K-tile t+1 issued one per phase in order A0,B0,A1,B1 into
//    the other buffer; quadrant order (0,0),(1,0),(1,1),(0,1) needs exactly
//    one newly-landed half per phase -> counted waits per K-tile:
//    vmcnt(6),(6),(6),none  (ledger: 8 outstanding at tile start + 2 just
//    issued, oldest half = 2 loads retired per wait). Last tile: (4),(2),(0).
//  - Register reuse across phases: B-frags kept ph0->ph1, A kept ph1->ph2,
//    B kept ph2->ph3 (32 ds_read_b128 / K-tile / wave).
//  - ph3: lgkmcnt(0)+barrier BEFORE MFMA => buf[cur] fully consumed
//    chip-wide before t+1 ph0 issues prefetch into it.
// Epilogues: Q/K scatter (same 32B-segment pattern as 128p kernel);
// V via 4 per-head LDS-transpose passes with the R4 key permutation.
__global__ __launch_bounds__(512, 2) void gemm256_kernel(
    const __hip_bfloat16* __restrict__ A,   // [8192][1024] bf16
    const __hip_bfloat16* __restrict__ Bt,  // [3072][1024] bf16
    __hip_bfloat16* __restrict__ Qb, __hip_bfloat16* __restrict__ Kb,
    __hip_bfloat16* __restrict__ Vt) {      // [B,H,d,T] key-permuted
  __shared__ __align__(16) char smem[131072];
  int tid = threadIdx.x;
  int nb = blockIdx.x;                 // 0..11: 0-3 Q, 4-7 K, 8-11 V
  int m0 = blockIdx.y * 256;
  const __hip_bfloat16* Asrc = A  + (size_t)m0 * N_EMBD;
  const __hip_bfloat16* Bsrc = Bt + (size_t)nb * 256 * N_EMBD;

  int lane = tid & 63, wv = tid >> 6, l16 = lane & 15, quad = lane >> 4;
  int swr = wv >> 2, swc = wv & 3;     // wave sub-pos in every quadrant
  int xg = l16 & 7;
  int offc0 = ((quad    ) ^ xg) * 8;   // k-chunk 0 physical group
  int offc1 = ((quad + 4) ^ xg) * 8;   // k-chunk 1
  int r0  = tid >> 3;                  // staging row 0..63 (and +64)
  int gsw = ((tid & 7) ^ (r0 & 7)) * 8;// swizzled global col offset
  int gln = (tid & 7) * 8;             // linear LDS col offset

  f32x4 acc[2][2][4][2];               // [qm][qn][mi][ni]
  #pragma unroll
  for (int a=0;a<2;++a)
    #pragma unroll
    for (int b=0;b<2;++b)
      #pragma unroll
      for (int c=0;c<4;++c)
        #pragma unroll
        for (int d=0;d<2;++d) acc[a][b][c][d] = (f32x4){0.f,0.f,0.f,0.f};

// stage one 128x64 half (2 glds16/thread): rows h*128+r0, h*128+r0+64
#define STG(srcbase, kk, hh_, dst_) do {                                      \
    const __hip_bfloat16* s_ = (srcbase) + (size_t)((hh_)*128 + r0)*N_EMBD + (kk) + gsw; \
    __hip_bfloat16* d_ = (dst_) + (hh_)*8192 + r0*64 + gln;                   \
    glds16(s_, d_);                                                           \
    glds16(s_ + (size_t)64*N_EMBD, d_ + 64*64);                               \
  } while (0)
#define RDA(qm_) do { _Pragma("unroll") for (int mi=0;mi<4;++mi) {            \
    const __hip_bfloat16* p_ = Acur + ((qm_)*128 + swr*64 + mi*16 + l16)*64;  \
    af[mi][0] = *(const s16x8*)(p_ + offc0);                                  \
    af[mi][1] = *(const s16x8*)(p_ + offc1); } } while (0)
#define RDB(qn_) do { _Pragma("unroll") for (int ni=0;ni<2;++ni) {            \
    const __hip_bfloat16* p_ = Bcur + ((qn_)*128 + swc*32 + ni*16 + l16)*64;  \
    bq[ni][0] = *(const s16x8*)(p_ + offc0);                                  \
    bq[ni][1] = *(const s16x8*)(p_ + offc1); } } while (0)
#define MM(qm_,qn_) do { _Pragma("unroll") for (int mi=0;mi<4;++mi)           \
    _Pragma("unroll") for (int ni=0;ni<2;++ni) {                              \
      acc[qm_][qn_][mi][ni] = __builtin_amdgcn_mfma_f32_16x16x32_bf16(af[mi][0], bq[ni][0], acc[qm_][qn_][mi][ni],0,0,0); \
      acc[qm_][qn_][mi][ni] = __builtin_amdgcn_mfma_f32_16x16x32_bf16(af[mi][1], bq[ni][1], acc[qm_][qn_][mi][ni],0,0,0); } } while (0)

  // prologue: K-tile 0, halves A0,B0,A1,B1 into buffer 0 (8 loads)
  {
    __hip_bfloat16* A0b = (__hip_bfloat16*)smem;
    __hip_bfloat16* B0b = (__hip_bfloat16*)(smem + 32768);
    STG(Asrc, 0, 0, A0b);
    STG(Bsrc, 0, 0, B0b);
    STG(Asrc, 0, 1, A0b);
    STG(Bsrc, 0, 1, B0b);
  }

  for (int t = 0; t < 16; ++t) {
    int kn = t*64 + 64;
    char* cb   = smem + (size_t)(t & 1) * 65536;
    char* nbuf = smem + (size_t)((t + 1) & 1) * 65536;
    const __hip_bfloat16* Acur = (const __hip_bfloat16*)cb;
    const __hip_bfloat16* Bcur = (const __hip_bfloat16*)(cb + 32768);
    __hip_bfloat16* An = (__hip_bfloat16*)nbuf;
    __hip_bfloat16* Bn = (__hip_bfloat16*)(nbuf + 32768);
    bool pf = (t < 15);
    s16x8 af[4][2], bq[2][2];

    // ---- phase 0: quadrant (0,0); needs A0,B0 of t; issue A0 of t+1 ----
    if (pf) { STG(Asrc, kn, 0, An); asm volatile("s_waitcnt vmcnt(6)" ::: "memory"); }
    else    {                       asm volatile("s_waitcnt vmcnt(4)" ::: "memory"); }
    __builtin_amdgcn_s_barrier();
    __builtin_amdgcn_sched_barrier(0);
    RDA(0); RDB(0);
    asm volatile("s_waitcnt lgkmcnt(0)" ::: "memory");
    __builtin_amdgcn_sched_barrier(0);
    __builtin_amdgcn_s_setprio(1); MM(0,0); __builtin_amdgcn_s_setprio(0);

    // ---- phase 1: quadrant (1,0); needs +A1; issue B0' ----
    if (pf) { STG(Bsrc, kn, 0, Bn); asm volatile("s_waitcnt vmcnt(6)" ::: "memory"); }
    else    {                       asm volatile("s_waitcnt vmcnt(2)" ::: "memory"); }
    __builtin_amdgcn_s_barrier();
    __builtin_amdgcn_sched_barrier(0);
    RDA(1);                               // B-frags kept in regs
    asm volatile("s_waitcnt lgkmcnt(0)" ::: "memory");
    __builtin_amdgcn_sched_barrier(0);
    __builtin_amdgcn_s_setprio(1); MM(1,0); __builtin_amdgcn_s_setprio(0);

    // ---- phase 2: quadrant (1,1); needs +B1; issue A1' ----
    if (pf) { STG(Asrc, kn, 1, An); asm volatile("s_waitcnt vmcnt(6)" ::: "memory"); }
    else    {                       asm volatile("s_waitcnt vmcnt(0)" ::: "memory"); }
    __builtin_amdgcn_s_barrier();
    __builtin_amdgcn_sched_barrier(0);
    RDB(1);                               // A-frags kept
    asm volatile("s_waitcnt lgkmcnt(0)" ::: "memory");
    __builtin_amdgcn_sched_barrier(0);
    __builtin_amdgcn_s_setprio(1); MM(1,1); __builtin_amdgcn_s_setprio(0);

    // ---- phase 3: quadrant (0,1); re-read A0; issue B1' ----
    // lgkm+barrier BEFORE MFMA: buf[cur] fully consumed chip-wide, so
    // t+1 ph0 may prefetch into it.
    if (pf) STG(Bsrc, kn, 1, Bn);
    RDA(0);                               // B-frags kept
    asm volatile("s_waitcnt lgkmcnt(0)" ::: "memory");
    __builtin_amdgcn_s_barrier();
    __builtin_amdgcn_sched_barrier(0);
    __builtin_amdgcn_s_setprio(1); MM(0,1); __builtin_amdgcn_s_setprio(0);
  }
#undef STG
#undef RDA
#undef RDB
#undef MM

  int which = nb >> 2;
  int bb = m0 >> 11, t0 = m0 & 2047;
  if (which < 2) {
    // Q/K scatter: frag (qm,qn,mi,ni,r): row/col per wave decomposition.
    __hip_bfloat16* outp = (which==0)?Qb:Kb;
    int nloc = (nb & 3) * 256;
    #pragma unroll
    for (int qm=0;qm<2;++qm)
      #pragma unroll
      for (int qn=0;qn<2;++qn)
        #pragma unroll
        for (int mi=0;mi<4;++mi)
          #pragma unroll
          for (int ni=0;ni<2;++ni) {
            int col = nloc + qn*128 + swc*32 + ni*16 + l16;
            int hh = col >> 6, dd = col & 63;
            int trow = t0 + qm*128 + swr*64 + mi*16 + quad*4;
            __hip_bfloat16* dst = outp + ((size_t)(bb*N_HEADS + hh)*TSEQ + trow)*HD + dd;
            #pragma unroll
            for (int r=0;r<4;++r)
              dst[(size_t)r*HD] = __float2bfloat16(acc[qm][qn][mi][ni][r]);
          }
  } else {
    // V: 4 per-head passes; LDS transpose Ts[64][264] + R4 key permutation.
    int hh0 = (nb & 3) * 4;
    __hip_bfloat16 (*Ts)[264] = (__hip_bfloat16(*)[264])smem;
    #pragma unroll
    for (int hd=0; hd<4; ++hd) {
      if (hd) __builtin_amdgcn_s_barrier();   // Ts free from prev pass reads
      if ((swc >> 1) == (hd & 1)) {
        int qn = hd >> 1;
        int ddb = (swc & 1) * 32;
        #pragma unroll
        for (int qm=0;qm<2;++qm)
          #pragma unroll
          for (int mi=0;mi<4;++mi)
            #pragma unroll
            for (int ni=0;ni<2;++ni) {
              int dd = ddb + ni*16 + l16;
              int trow = qm*128 + swr*64 + mi*16 + quad*4;
              #pragma unroll
              for (int r=0;r<4;++r)
                Ts[dd][trow + r] = __float2bfloat16(acc[qm][qn][mi][ni][r]);
            }
      }
      __syncthreads();
      int dd = tid >> 3, tcb = (tid & 7) * 32;
      __hip_bfloat16* dst = Vt + ((size_t)(bb*N_HEADS + hh0 + hd)*HD + dd)*TSEQ + t0;
      #pragma unroll
      for (int pb=0; pb<8; ++pb) {
        int q  = tcb + pb*4;
        int pp = q & 63;
        int key = (q & 192) | (pp & 32) | ((pp & 4) << 2) | ((pp & 24) >> 1);
        *(uint2*)(dst + q) = *(const uint2*)&Ts[dd][key];
      }
    }
  }
}

// ---- old 128p GEMM kept for the proj matmul (mode 1); mode-0 path dead ----
__global__ __launch_bounds__(256) void gemm_kernel(
    const __hip_bfloat16* __restrict__ A,
    const __hip_bfloat16* __restrict__ Bt,
    __hip_bfloat16* __restrict__ Qb, __hip_bfloat16* __restrict__ Kb,
    __hip_bfloat16* __restrict__ Vt,
    float* __restrict__ out, const float* __restrict__ bias, int mode) {
  __shared__ __align__(16) char smem[32768];
  __hip_bfloat16* Alin = (__hip_bfloat16*)smem;            // 128x64
  __hip_bfloat16* Blin = (__hip_bfloat16*)(smem + 16384);  // 128x64
  int tid = threadIdx.x;
  int m0 = blockIdx.y*128, n0 = blockIdx.x*128;
  int w = tid>>6, lane = tid&63, l16 = lane&15, quad = lane>>4;
  int wr = w>>1, wc = w&1;
  int xg = l16 & 7;
  int off0 = ((quad    ) ^ xg)*8;
  int off1 = ((quad + 4) ^ xg)*8;
  f32x4 acc[4][4];
  #pragma unroll
  for (int mi=0;mi<4;++mi)
    #pragma unroll
    for (int ni=0;ni<4;++ni) acc[mi][ni] = (f32x4){0.f,0.f,0.f,0.f};

  for (int k0=0; k0<N_EMBD; k0+=64) {
    __syncthreads();
    #pragma unroll
    for (int rd=0; rd<4; ++rd) {
      int slot = rd*256 + tid;
      int row  = slot>>3;
      int gc8  = ((tid&7) ^ (row&7))*8;
      glds16(A  + (size_t)(m0+row)*N_EMBD + k0 + gc8, Alin + slot*8);
      glds16(Bt + (size_t)(n0+row)*N_EMBD + k0 + gc8, Blin + slot*8);
    }
    __syncthreads();
    #pragma unroll
    for (int c=0;c<2;++c) {
      int off = c ? off1 : off0;
      s16x8 af[4], bfr[4];
      #pragma unroll
      for (int mi=0;mi<4;++mi)
        af[mi] = *(const s16x8*)(Alin + (wr*64+mi*16+l16)*64 + off);
      #pragma unroll
      for (int ni=0;ni<4;++ni)
        bfr[ni] = *(const s16x8*)(Blin + (wc*64+ni*16+l16)*64 + off);
      #pragma unroll
      for (int mi=0;mi<4;++mi)
        #pragma unroll
        for (int ni=0;ni<4;++ni)
          acc[mi][ni] = __builtin_amdgcn_mfma_f32_16x16x32_bf16(af[mi], bfr[ni], acc[mi][ni],0,0,0);
    }
  }

  if (mode == 0) {
    // dead path (QKV moved to gemm256_kernel); retained unmodified.
  } else {
    #pragma unroll
    for (int mi=0;mi<4;++mi) {
      #pragma unroll
      for (int ni=0;ni<4;++ni) {
        int col = n0 + wc*64 + ni*16 + l16;
        float bs = bias[col];
        #pragma unroll
        for (int r=0;r<4;++r) {
          int m = m0 + wr*64 + mi*16 + quad*4 + r;
          out[(size_t)m*N_EMBD + col] = acc[mi][ni][r] + bs;
        }
      }
    }
  }
}

// ---- MFMA causal flash attention (R5 configuration; R7 setprio reverted —
// cross-run noise made its effect indistinguishable from -5us regression,
// and m190 precedent makes it suspect) ----
__global__ __launch_bounds__(256) void attn_kernel(
    const __hip_bfloat16* __restrict__ Qb, const __hip_bfloat16* __restrict__ Kb,
    const __hip_bfloat16* __restrict__ Vt, __hip_bfloat16* __restrict__ Yb) {
  __shared__ __align__(16) __hip_bfloat16 Ks[2][64][64];   // [buf][key][d] swizzled
  __shared__ __align__(16) __hip_bfloat16 Vs[2][64][64];   // [buf][d][pos] swizzled
  int tid = threadIdx.x;
  int wgid = blockIdx.x;
  int qb = (int)((0x01237564AB89CDEFull >> ((wgid>>6)*4)) & 15);  // R5 LJF perm
  int h  = (wgid>>2) & 15;
  int b  = wgid & 3;
  int q0 = qb*128;
  size_t bhT  = (size_t)(b*N_HEADS + h)*TSEQ;
  size_t bhHD = (size_t)(b*N_HEADS + h)*HD;
  int lane = tid&63, w = tid>>6, l16 = lane&15, quad = lane>>4;
  int wq = w*32;
  int xg = l16 & 7;
  int off0 = ((quad    ) ^ xg)*8;
  int off1 = ((quad + 4) ^ xg)*8;

  int slot0 = tid,        row0 = slot0>>3, gcA = ((tid&7) ^ (row0&7))*8;
  int slot1 = 256 + tid,  row1 = slot1>>3, gcB = ((tid&7) ^ (row1&7))*8;

  s16x8 qf[2][2];
  #pragma unroll
  for (int mi=0;mi<2;++mi) {
    const __hip_bfloat16* qrow = Qb + (bhT + q0 + wq + mi*16 + l16)*HD;
    qf[mi][0] = *(const s16x8*)(qrow + quad*8);
    qf[mi][1] = *(const s16x8*)(qrow + 32 + quad*8);
  }

  f32x4 z4 = {0.f,0.f,0.f,0.f};
  f32x4 oacc[4][2];
  #pragma unroll
  for (int nd=0;nd<4;++nd) { oacc[nd][0]=z4; oacc[nd][1]=z4; }
  float lsum[2] = {0.f, 0.f};

  int ntiles = 2*qb + 2;

  {
    glds16(Kb + (bhT + 0 + row0)*HD + gcA,    &Ks[0][0][0] + slot0*8);
    glds16(Vt + (bhHD + row0)*TSEQ + 0 + gcA, &Vs[0][0][0] + slot0*8);
    glds16(Kb + (bhT + 0 + row1)*HD + gcB,    &Ks[0][0][0] + slot1*8);
    glds16(Vt + (bhHD + row1)*TSEQ + 0 + gcB, &Vs[0][0][0] + slot1*8);
  }

  for (int t=0; t<ntiles; ++t) {
    int cur = t&1;
    int k0 = t*64;
    if (t+1 < ntiles) {
      int kn = k0 + 64;
      glds16(Kb + (bhT + kn + row0)*HD + gcA,     &Ks[cur^1][0][0] + slot0*8);
      glds16(Vt + (bhHD + row0)*TSEQ + kn + gcA,  &Vs[cur^1][0][0] + slot0*8);
      glds16(Kb + (bhT + kn + row1)*HD + gcB,     &Ks[cur^1][0][0] + slot1*8);
      glds16(Vt + (bhHD + row1)*TSEQ + kn + gcB,  &Vs[cur^1][0][0] + slot1*8);
      asm volatile("s_waitcnt vmcnt(4)" ::: "memory");
    } else {
      asm volatile("s_waitcnt vmcnt(0)" ::: "memory");
    }
    __builtin_amdgcn_s_barrier();
    __builtin_amdgcn_sched_barrier(0);

    const __hip_bfloat16* Kc = &Ks[cur][0][0];
    const __hip_bfloat16* Vc = &Vs[cur][0][0];

    f32x4 sacc[4][2];
    #pragma unroll
    for (int ni=0; ni<4; ++ni) {
      s16x8 kb0 = *(const s16x8*)(Kc + (ni*16+l16)*64 + off0);
      s16x8 kb1 = *(const s16x8*)(Kc + (ni*16+l16)*64 + off1);
      #pragma unroll
      for (int mi=0; mi<2; ++mi) {
        f32x4 s = z4;
        s = __builtin_amdgcn_mfma_f32_16x16x32_bf16(kb0, qf[mi][0], s,0,0,0);
        s = __builtin_amdgcn_mfma_f32_16x16x32_bf16(kb1, qf[mi][1], s,0,0,0);
        sacc[ni][mi] = s;
      }
    }

    unsigned pkw[2][4][2];
    if (q0 + wq >= k0 + 63) {
      #pragma unroll
      for (int ni=0; ni<4; ++ni) {
        #pragma unroll
        for (int mi=0; mi<2; ++mi) {
          float e0 = exp_scaled(sacc[ni][mi][0]);
          float e1 = exp_scaled(sacc[ni][mi][1]);
          float e2 = exp_scaled(sacc[ni][mi][2]);
          float e3 = exp_scaled(sacc[ni][mi][3]);
          lsum[mi] += (e0+e1)+(e2+e3);
          pkw[mi][ni][0] = cvtpk(e0, e1);
          pkw[mi][ni][1] = cvtpk(e2, e3);
        }
      }
    } else {
      #pragma unroll
      for (int ni=0; ni<4; ++ni) {
        int kbase = k0 + ni*16 + quad*4;
        #pragma unroll
        for (int mi=0; mi<2; ++mi) {
          int qrow = q0 + wq + mi*16 + l16;
          float e0 = (qrow >= kbase    ) ? exp_scaled(sacc[ni][mi][0]) : 0.f;
          float e1 = (qrow >= kbase + 1) ? exp_scaled(sacc[ni][mi][1]) : 0.f;
          float e2 = (qrow >= kbase + 2) ? exp_scaled(sacc[ni][mi][2]) : 0.f;
          float e3 = (qrow >= kbase + 3) ? exp_scaled(sacc[ni][mi][3]) : 0.f;
          lsum[mi] += (e0+e1)+(e2+e3);
          pkw[mi][ni][0] = cvtpk(e0, e1);
          pkw[mi][ni][1] = cvtpk(e2, e3);
        }
      }
    }

    union U8 { s16x8 v; unsigned u[4]; };
    U8 pf[2][2];
    #pragma unroll
    for (int c=0; c<2; ++c)
      #pragma unroll
      for (int mi=0; mi<2; ++mi) {
        pf[c][mi].u[0] = pkw[mi][2*c  ][0];
        pf[c][mi].u[1] = pkw[mi][2*c  ][1];
        pf[c][mi].u[2] = pkw[mi][2*c+1][0];
        pf[c][mi].u[3] = pkw[mi][2*c+1][1];
      }
    #pragma unroll
    for (int nd=0; nd<4; ++nd) {
      const __hip_bfloat16* vrow = Vc + (nd*16 + l16)*64;
      s16x8 vb0 = *(const s16x8*)(vrow + off0);
      s16x8 vb1 = *(const s16x8*)(vrow + off1);
      oacc[nd][0] = __builtin_amdgcn_mfma_f32_16x16x32_bf16(vb0, pf[0][0].v, oacc[nd][0],0,0,0);
      oacc[nd][1] = __builtin_amdgcn_mfma_f32_16x16x32_bf16(vb0, pf[0][1].v, oacc[nd][1],0,0,0);
      oacc[nd][0] = __builtin_amdgcn_mfma_f32_16x16x32_bf16(vb1, pf[1][0].v, oacc[nd][0],0,0,0);
      oacc[nd][1] = __builtin_amdgcn_mfma_f32_16x16x32_bf16(vb1, pf[1][1].v, oacc[nd][1],0,0,0);
    }

    asm volatile("s_waitcnt lgkmcnt(0)" ::: "memory");
    __builtin_amdgcn_s_barrier();
    __builtin_amdgcn_sched_barrier(0);
  }

  #pragma unroll
  for (int mi=0; mi<2; ++mi) {
    lsum[mi] += __shfl_xor(lsum[mi], 16);
    lsum[mi] += __shfl_xor(lsum[mi], 32);
  }

  #pragma unroll
  for (int mi=0; mi<2; ++mi) {
    float inv = 1.f / lsum[mi];
    int tq = q0 + wq + mi*16 + l16;
    __hip_bfloat16* yr = Yb + ((size_t)(b*TSEQ + tq))*N_EMBD + h*HD + quad*4;
    #pragma unroll
    for (int nd=0; nd<4; ++nd) {
      uint2 o;
      o.x = cvtpk(oacc[nd][mi][0]*inv, oacc[nd][mi][1]*inv);
      o.y = cvtpk(oacc[nd][mi][2]*inv, oacc[nd][mi][3]*inv);
      *(uint2*)(yr + nd*16) = o;
    }
  }
}

extern "C" void kernel_launch(void* const* d_in, const int* in_sizes, int n_in,
                              void* d_out, int out_size, void* d_ws, size_t ws_size,
                              hipStream_t stream) {
  const float* x  = (const float*)d_in[0];
  const float* Wq = (const float*)d_in[1];
  const float* Wk = (const float*)d_in[2];
  const float* Wv = (const float*)d_in[3];
  const float* Wp = (const float*)d_in[4];
  const float* bp = (const float*)d_in[5];

  char* w = (char*)d_ws;
  __hip_bfloat16* xb    = (__hip_bfloat16*)w;  w += (size_t)M_TOT*N_EMBD*2;   // 16 MB
  __hip_bfloat16* wqkvt = (__hip_bfloat16*)w;  w += (size_t)3*N_EMBD*N_EMBD*2;// 6 MB
  __hip_bfloat16* wpt   = (__hip_bfloat16*)w;  w += (size_t)N_EMBD*N_EMBD*2;  // 2 MB
  __hip_bfloat16* Qb    = (__hip_bfloat16*)w;  w += (size_t)M_TOT*N_EMBD*2;   // 16 MB
  __hip_bfloat16* Kb    = (__hip_bfloat16*)w;  w += (size_t)M_TOT*N_EMBD*2;   // 16 MB
  __hip_bfloat16* Vt    = (__hip_bfloat16*)w;  w += (size_t)M_TOT*N_EMBD*2;   // 16 MB [B,H,d,T] permuted
  __hip_bfloat16* Yb    = (__hip_bfloat16*)w;                                  // 16 MB (88 MB total)

  xcast_kernel<<<dim3(M_TOT*N_EMBD/1024), dim3(256), 0, stream>>>(x, xb);
  wcast_kernel<<<dim3(32,32,4), dim3(32,8), 0, stream>>>(Wq,Wk,Wv,Wp,wqkvt,wpt);
  gemm256_kernel<<<dim3(12,32), dim3(512), 0, stream>>>(xb, wqkvt, Qb,Kb,Vt);
  attn_kernel<<<dim3(1024), dim3(256), 0, stream>>>(Qb,Kb,Vt,Yb);
  gemm_kernel<<<dim3(8,64), dim3(256), 0, stream>>>(Yb, wpt, nullptr,nullptr,nullptr,
                                                    (float*)d_out, bp, 1);
}